// Round 4
// baseline (219.136 us; speedup 1.0000x reference)
//
#include <hip/hip_runtime.h>
#include <hip/hip_fp16.h>

// GCN: 100K nodes, 2.5M edges, dims 4 -> 32 -> (32x32 conv x3) -> 3.
// R16: 16-bit quad CSR, 4-phase segmented gather, NBLK=512 scatter-free
//      build, fp16 g, fp32 accumulate.  [219 us]
// R19: hierarchical wave-shuffle scans in build (1-2 barriers, was 9-20).
//      [215.7 us]
// R20: HALF CSR (HDIV=50000, still < 64K so ushort offsets hold). 4 quads
//      -> 2 halves: per-phase L2 hot set 1.6->3.2 MB (still <= 4MB/XCD),
//      pipeline fills + scalar tails per node halve (4->2), wave divergence
//      sum-of-phase-maxes drops ~47 -> ~41 edge-slots. Build key space
//      1024 -> 512 (key by compare, not divide). Gather inner loop is
//      byte-identical R16 form.

constexpr int N_NODES = 100000;
constexpr int N_EDGES = 2500000;
constexpr int HDIV    = 50000;                             // src half divisor
constexpr int BUCKET  = 256;
constexpr int NBUCK   = (N_NODES + BUCKET - 1) / BUCKET;   // 391
constexpr int NBLK    = 512;                               // build blocks
constexpr int CHUNK   = (N_EDGES + NBLK - 1) / NBLK;       // 4883
constexpr int SCAP    = 8192;                              // sortdeg LDS stage cap
constexpr int PERLANE = NBLK / 64;                         // 8

// ---- build K1: per-block LDS counting sort by bucket; contiguous write ----
__global__ __launch_bounds__(256) void k_binfill(const int* __restrict__ ei,
                                                 int* __restrict__ binned,
                                                 int* __restrict__ blkbin,
                                                 int* __restrict__ locoff) {
    __shared__ int cnt[NBUCK];
    __shared__ int cur[NBUCK];
    __shared__ int wsum[4];
    __shared__ int stage[CHUNK];
    int tid = threadIdx.x;
    int blk = blockIdx.x;
    int beg = blk * CHUNK;
    int end = min(beg + CHUNK, N_EDGES);
    int m = end - beg;

    for (int i = tid; i < NBUCK; i += 256) cnt[i] = 0;
    __syncthreads();
    for (int e = beg + tid; e < end; e += 256)
        atomicAdd(&cnt[ei[N_EDGES + e] >> 8], 1);
    __syncthreads();

    // hierarchical shfl scan over 512 slots (2 per thread), 1 barrier.
    int c0 = (2 * tid     < NBUCK) ? cnt[2 * tid]     : 0;
    int c1 = (2 * tid + 1 < NBUCK) ? cnt[2 * tid + 1] : 0;
    int s  = c0 + c1;
    int incl = s;
#pragma unroll
    for (int o = 1; o < 64; o <<= 1) {
        int tm = __shfl_up(incl, o);
        if ((tid & 63) >= o) incl += tm;
    }
    if ((tid & 63) == 63) wsum[tid >> 6] = incl;
    __syncthreads();
    int wexcl = 0;
#pragma unroll
    for (int wi = 0; wi < 4; ++wi) wexcl += (wi < (tid >> 6)) ? wsum[wi] : 0;
    int texcl = wexcl + incl - s;              // exclusive prefix at slot 2*tid
    {
        int i = 2 * tid;
        if (i < NBUCK) {
            cur[i] = texcl;
            blkbin[i * NBLK + blk] = c0;
            locoff[blk * NBUCK + i] = beg + texcl;
        }
        i = 2 * tid + 1;
        if (i < NBUCK) {
            int e1 = texcl + c0;
            cur[i] = e1;
            blkbin[i * NBLK + blk] = c1;
            locoff[blk * NBUCK + i] = beg + e1;
        }
    }
    __syncthreads();

    for (int e = beg + tid; e < end; e += 256) {
        int sv = ei[e];
        int d = ei[N_EDGES + e];
        int pos = atomicAdd(&cur[d >> 8], 1);
        stage[pos] = (sv << 8) | (d & 255);    // src<17b><<8 | dst_local<8b>
    }
    __syncthreads();
    for (int i = tid; i < m; i += 256) binned[beg + i] = stage[i];  // coalesced
}

// ---- build K2: per-bin total + per-bin run-placement prefix (one wave/bin) ----
__global__ __launch_bounds__(256) void k_binwave(const int* __restrict__ blkbin,
                                                 int* __restrict__ bintot,
                                                 int* __restrict__ blkpos) {
    int w = threadIdx.x >> 6, lane = threadIdx.x & 63;
    int bin = blockIdx.x * 4 + w;
    if (bin >= NBUCK) return;
    int v[PERLANE];
#pragma unroll
    for (int i = 0; i < PERLANE; ++i) v[i] = blkbin[bin * NBLK + lane * PERLANE + i];
    int mysum = 0;
#pragma unroll
    for (int i = 0; i < PERLANE; ++i) mysum += v[i];
    int pre = mysum;
#pragma unroll
    for (int o = 1; o < 64; o <<= 1) {
        int t = __shfl_up(pre, o);
        if (lane >= o) pre += t;
    }
    int excl = pre - mysum;
    int run = excl;
#pragma unroll
    for (int i = 0; i < PERLANE; ++i) {
        blkpos[bin * NBLK + lane * PERLANE + i] = run;
        run += v[i];
    }
    if (lane == 63) bintot[bin] = pre;
}

// ---- build K3: per-bucket 512-key sort (dst_local*2 + src_half) ----
// Emits ushort csr (src - half*HDIV). Computes its own bucket offset.
__global__ __launch_bounds__(512) void k_sortdeg(const int* __restrict__ binned,
                                                 const int* __restrict__ blkbin,
                                                 const int* __restrict__ blkpos,
                                                 const int* __restrict__ locoff,
                                                 const int* __restrict__ bintot,
                                                 unsigned short* __restrict__ csr16,
                                                 int* __restrict__ rowseg,
                                                 float* __restrict__ dinv) {
    __shared__ int stage[SCAP];      // 32 KB
    __shared__ int runlen[NBLK];     // 2 KB
    __shared__ int runpos[NBLK];     // 2 KB
    __shared__ int cnt[512];         // 2 KB
    __shared__ int cur[512];         // 2 KB
    __shared__ int wred[8];
    __shared__ int wtot[8];
    int t = threadIdx.x;
    int b = blockIdx.x;

    // bucket offset via wave-reduce (1 barrier)
    int part = 0;
    for (int i = t; i < b; i += 512) part += bintot[i];
#pragma unroll
    for (int o = 32; o > 0; o >>= 1) part += __shfl_xor(part, o);
    if ((t & 63) == 0) wred[t >> 6] = part;

    if (t < NBLK) {
        runlen[t] = blkbin[b * NBLK + t];
        runpos[t] = blkpos[b * NBLK + t];
    }
    cnt[t] = 0;
    __syncthreads();

    int beg = 0;
#pragma unroll
    for (int wi = 0; wi < 8; ++wi) beg += wred[wi];
    int end = beg + bintot[b];
    int total = end - beg;
    bool fits = (total <= SCAP);

    if (fits) {
        for (int blk = t; blk < NBLK; blk += 512) {
            int len = runlen[blk];
            int srcp = locoff[blk * NBUCK + b];
            int dstp = runpos[blk];
            for (int i = 0; i < len; ++i) stage[dstp + i] = binned[srcp + i];
        }
        __syncthreads();
        for (int k = t; k < total; k += 512) {
            int p = stage[k];
            int key = ((p & 255) << 1) | (((p >> 8) >= HDIV) ? 1 : 0);
            atomicAdd(&cnt[key], 1);
        }
    } else {   // overflow fallback (statistically never)
        for (int blk = t; blk < NBLK; blk += 512) {
            int len = runlen[blk];
            int srcp = locoff[blk * NBUCK + b];
            for (int i = 0; i < len; ++i) {
                int p = binned[srcp + i];
                int key = ((p & 255) << 1) | (((p >> 8) >= HDIV) ? 1 : 0);
                atomicAdd(&cnt[key], 1);
            }
        }
    }
    __syncthreads();

    // 512-key exclusive scan, 1 slot/thread, hierarchical shfl (1 barrier)
    int c = cnt[t];
    int incl = c;
#pragma unroll
    for (int o = 1; o < 64; o <<= 1) {
        int tm = __shfl_up(incl, o);
        if ((t & 63) >= o) incl += tm;
    }
    if ((t & 63) == 63) wtot[t >> 6] = incl;
    __syncthreads();
    int wexcl = 0;
#pragma unroll
    for (int wi = 0; wi < 8; ++wi) wexcl += (wi < (t >> 6)) ? wtot[wi] : 0;
    int excl = wexcl + incl - c;
    cur[t] = excl;
    {
        int dl = t >> 1, h = t & 1;
        int n = b * BUCKET + dl;
        if (n < N_NODES) {
            rowseg[n * 2 + h] = beg + excl;
            if (h == 0) {
                int deg = c + cnt[t + 1];            // sum of the 2 halves
                dinv[n] = rsqrtf((float)(deg + 1));  // +1 self-loop
            }
        }
    }
    if (b == NBUCK - 1 && t == 0) rowseg[(size_t)N_NODES * 2] = end;  // sentinel
    __syncthreads();

    if (fits) {
        for (int k = t; k < total; k += 512) {
            int p = stage[k];
            int src = p >> 8;
            int h = (src >= HDIV) ? 1 : 0;
            int key = ((p & 255) << 1) | h;
            int pos = atomicAdd(&cur[key], 1);
            csr16[beg + pos] = (unsigned short)(src - (h ? HDIV : 0));
        }
    } else {
        for (int blk = t; blk < NBLK; blk += 512) {
            int len = runlen[blk];
            int srcp = locoff[blk * NBUCK + b];
            for (int i = 0; i < len; ++i) {
                int p = binned[srcp + i];
                int src = p >> 8;
                int h = (src >= HDIV) ? 1 : 0;
                int key = ((p & 255) << 1) | h;
                int pos = atomicAdd(&cur[key], 1);
                csr16[beg + pos] = (unsigned short)(src - (h ? HDIV : 0));
            }
        }
    }
}

// ================= dense helpers =================
__device__ inline void store_half8(__half* p, const float* v) {
    __half2 h[4];
#pragma unroll
    for (int i = 0; i < 4; ++i)
        h[i] = __floats2half2_rn(v[2 * i], v[2 * i + 1]);
    *(float4*)p = *(float4*)h;
}

__device__ inline void acc_half8(float* acc, float4 raw) {
    __half2* hp = (__half2*)&raw;
#pragma unroll
    for (int i = 0; i < 4; ++i) {
        float2 f = __half22float2(hp[i]);
        acc[2 * i]     += f.x;
        acc[2 * i + 1] += f.y;
    }
}

// t = relu(x@Wfc1 + bfc1); g = half( dinv * (t@Wc1) )
__global__ __launch_bounds__(256) void k_fc1_conv1(
        const float* __restrict__ x,
        const float* __restrict__ Wfc1, const float* __restrict__ bfc1,
        const float* __restrict__ Wc1, const float* __restrict__ dinv,
        __half* __restrict__ g) {
    __shared__ float  sWf[128];
    __shared__ float  sbf[32];
    __shared__ float4 sW[256];
    if (threadIdx.x < 128) sWf[threadIdx.x] = Wfc1[threadIdx.x];
    if (threadIdx.x < 32)  sbf[threadIdx.x] = bfc1[threadIdx.x];
    sW[threadIdx.x] = ((const float4*)Wc1)[threadIdx.x];
    __syncthreads();

    int n = blockIdx.x * 256 + threadIdx.x;
    if (n >= N_NODES) return;

    float4 xin = *(const float4*)(x + (size_t)n * 4);
    float t[32];
#pragma unroll
    for (int j = 0; j < 32; ++j) {
        float a = fmaf(xin.x, sWf[j], sbf[j]);
        a = fmaf(xin.y, sWf[32 + j], a);
        a = fmaf(xin.z, sWf[64 + j], a);
        a = fmaf(xin.w, sWf[96 + j], a);
        t[j] = fmaxf(a, 0.0f);
    }
    float o[32];
#pragma unroll
    for (int j = 0; j < 32; ++j) o[j] = 0.f;
#pragma unroll
    for (int k = 0; k < 32; ++k) {
        float a = t[k];
#pragma unroll
        for (int q = 0; q < 8; ++q) {
            float4 w = sW[k * 8 + q];
            o[q * 4 + 0] = fmaf(a, w.x, o[q * 4 + 0]);
            o[q * 4 + 1] = fmaf(a, w.y, o[q * 4 + 1]);
            o[q * 4 + 2] = fmaf(a, w.z, o[q * 4 + 2]);
            o[q * 4 + 3] = fmaf(a, w.w, o[q * 4 + 3]);
        }
    }
    float dv = dinv[n];
#pragma unroll
    for (int j = 0; j < 32; ++j) o[j] *= dv;
    __half* gp = g + (size_t)n * 32;
    store_half8(gp,      o);
    store_half8(gp + 8,  o + 8);
    store_half8(gp + 16, o + 16);
    store_half8(gp + 24, o + 24);
}

// ---- edge-segment accumulate over ushort csr: src = base + off ----
// (exact R16 form: 4-wide pipelined main loop + scalar remainder)
__device__ inline void gather_seg(int beg, int end, int base,
                                  const unsigned short* __restrict__ csr16,
                                  const __half* __restrict__ gin, int sub, float* acc) {
    int k = beg;
    int stop = beg + ((end - beg) & ~3);
    if (k < stop) {
        int s0 = base + csr16[k],     s1 = base + csr16[k + 1];
        int s2 = base + csr16[k + 2], s3 = base + csr16[k + 3];
        k += 4;
        while (k < stop) {
            float4 r0 = *(const float4*)(gin + (size_t)s0 * 32 + sub * 8);
            float4 r1 = *(const float4*)(gin + (size_t)s1 * 32 + sub * 8);
            float4 r2 = *(const float4*)(gin + (size_t)s2 * 32 + sub * 8);
            float4 r3 = *(const float4*)(gin + (size_t)s3 * 32 + sub * 8);
            s0 = base + csr16[k];     s1 = base + csr16[k + 1];
            s2 = base + csr16[k + 2]; s3 = base + csr16[k + 3];
            acc_half8(acc, r0); acc_half8(acc, r1);
            acc_half8(acc, r2); acc_half8(acc, r3);
            k += 4;
        }
        float4 r0 = *(const float4*)(gin + (size_t)s0 * 32 + sub * 8);
        float4 r1 = *(const float4*)(gin + (size_t)s1 * 32 + sub * 8);
        float4 r2 = *(const float4*)(gin + (size_t)s2 * 32 + sub * 8);
        float4 r3 = *(const float4*)(gin + (size_t)s3 * 32 + sub * 8);
        acc_half8(acc, r0); acc_half8(acc, r1);
        acc_half8(acc, r2); acc_half8(acc, r3);
    }
    for (; k < end; ++k) {
        int s = base + csr16[k];
        float4 r = *(const float4*)(gin + (size_t)s * 32 + sub * 8);
        acc_half8(acc, r);
    }
}

// ---- 2-phase soft gather + mid MLP: 4 threads/node, 64 nodes/block ----
// Per-segment calls act as wave-level phase barriers (SIMT lockstep).
__global__ __launch_bounds__(256) void k_gather_mid(
        const int* __restrict__ rowseg,
        const unsigned short* __restrict__ csr16, const __half* __restrict__ gin,
        const float* __restrict__ dinv,
        const float* __restrict__ b, const float* __restrict__ W,
        __half* __restrict__ gout) {
    __shared__ float sS[64 * 33];
    __shared__ float sW[1024];
    __shared__ float sb[32];
    for (int i = threadIdx.x; i < 1024; i += 256) sW[i] = W[i];
    if (threadIdx.x < 32) sb[threadIdx.x] = b[threadIdx.x];

    int nl = threadIdx.x >> 2;
    int sub = threadIdx.x & 3;
    int n = blockIdx.x * 64 + nl;
    float acc[8];
    if (n < N_NODES) {
        float4 self = *(const float4*)(gin + (size_t)n * 32 + sub * 8);
        {
            __half2* hp = (__half2*)&self;
#pragma unroll
            for (int i = 0; i < 4; ++i) {
                float2 f = __half22float2(hp[i]);
                acc[2 * i] = f.x;
                acc[2 * i + 1] = f.y;
            }
        }
        int2 s01 = *(const int2*)(rowseg + (size_t)n * 2);
        int send = rowseg[(size_t)n * 2 + 2];            // next start / sentinel
        gather_seg(s01.x, s01.y, 0,    csr16, gin, sub, acc);   // half 0
        gather_seg(s01.y, send, HDIV,  csr16, gin, sub, acc);   // half 1
#pragma unroll
        for (int i = 0; i < 8; ++i) sS[nl * 33 + sub * 8 + i] = acc[i];
    }
    __syncthreads();

    if (n >= N_NODES) return;
    float dv = dinv[n];
    float t[32];
#pragma unroll
    for (int kk = 0; kk < 32; ++kk)
        t[kk] = fmaxf(fmaf(dv, sS[nl * 33 + kk], sb[kk]), 0.0f);
    float o[8];
#pragma unroll
    for (int j = 0; j < 8; ++j) o[j] = 0.f;
#pragma unroll
    for (int kk = 0; kk < 32; ++kk) {
        float a = t[kk];
#pragma unroll
        for (int j = 0; j < 8; ++j)
            o[j] = fmaf(a, sW[kk * 32 + sub * 8 + j], o[j]);
    }
#pragma unroll
    for (int j = 0; j < 8; ++j) o[j] *= dv;
    store_half8(gout + (size_t)n * 32 + sub * 8, o);
}

// ---- 2-phase soft gather + final layer ----
__global__ __launch_bounds__(256) void k_gather_out(
        const int* __restrict__ rowseg,
        const unsigned short* __restrict__ csr16, const __half* __restrict__ gin,
        const float* __restrict__ dinv,
        const float* __restrict__ bc3, const float* __restrict__ Wfc2,
        const float* __restrict__ bfc2, float* __restrict__ out) {
    __shared__ float sS[64 * 33];
    __shared__ float sW[96];
    __shared__ float sb[32];
    __shared__ float sb2[3];
    if (threadIdx.x < 96) sW[threadIdx.x] = Wfc2[threadIdx.x];
    if (threadIdx.x < 32) sb[threadIdx.x] = bc3[threadIdx.x];
    if (threadIdx.x < 3)  sb2[threadIdx.x] = bfc2[threadIdx.x];

    int nl = threadIdx.x >> 2;
    int sub = threadIdx.x & 3;
    int n = blockIdx.x * 64 + nl;
    float acc[8];
    if (n < N_NODES) {
        float4 self = *(const float4*)(gin + (size_t)n * 32 + sub * 8);
        {
            __half2* hp = (__half2*)&self;
#pragma unroll
            for (int i = 0; i < 4; ++i) {
                float2 f = __half22float2(hp[i]);
                acc[2 * i] = f.x;
                acc[2 * i + 1] = f.y;
            }
        }
        int2 s01 = *(const int2*)(rowseg + (size_t)n * 2);
        int send = rowseg[(size_t)n * 2 + 2];
        gather_seg(s01.x, s01.y, 0,    csr16, gin, sub, acc);
        gather_seg(s01.y, send, HDIV,  csr16, gin, sub, acc);
#pragma unroll
        for (int i = 0; i < 8; ++i) sS[nl * 33 + sub * 8 + i] = acc[i];
    }
    __syncthreads();

    if (n >= N_NODES || sub != 0) return;
    float dv = dinv[n];
    float t[32];
#pragma unroll
    for (int kk = 0; kk < 32; ++kk)
        t[kk] = fmaxf(fmaf(dv, sS[nl * 33 + kk], sb[kk]), 0.0f);
    float o0 = sb2[0], o1 = sb2[1], o2 = sb2[2];
#pragma unroll
    for (int kk = 0; kk < 32; ++kk) {
        o0 = fmaf(t[kk], sW[kk * 3 + 0], o0);
        o1 = fmaf(t[kk], sW[kk * 3 + 1], o1);
        o2 = fmaf(t[kk], sW[kk * 3 + 2], o2);
    }
    out[(size_t)n * 3 + 0] = o0;
    out[(size_t)n * 3 + 1] = o1;
    out[(size_t)n * 3 + 2] = o2;
}

extern "C" void kernel_launch(void* const* d_in, const int* in_sizes, int n_in,
                              void* d_out, int out_size, void* d_ws, size_t ws_size,
                              hipStream_t stream) {
    const float* x    = (const float*)d_in[0];
    const int*   ei   = (const int*)d_in[1];
    const float* Wfc1 = (const float*)d_in[2];
    const float* bfc1 = (const float*)d_in[3];
    const float* Wc1  = (const float*)d_in[4];
    const float* bc1  = (const float*)d_in[5];
    const float* Wc2  = (const float*)d_in[6];
    const float* bc2  = (const float*)d_in[7];
    const float* Wc3  = (const float*)d_in[8];
    const float* bc3  = (const float*)d_in[9];
    const float* Wfc2 = (const float*)d_in[10];
    const float* bfc2 = (const float*)d_in[11];
    float* out = (float*)d_out;

    char* ws = (char*)d_ws;
    const size_t grow = (size_t)N_NODES * 32 * sizeof(__half);   // 6.4 MB
    size_t off = 0;
    __half* gA     = (__half*)(ws + off); off += grow;
    __half* gB     = (__half*)(ws + off); off += grow;
    int*   binned  = (int*)  (ws + off); off += (size_t)NBLK * CHUNK * sizeof(int);
    unsigned short* csr16 = (unsigned short*)(ws + off);
    off += ((size_t)N_EDGES + 8) * sizeof(unsigned short);
    float* dinv    = (float*)(ws + off); off += (size_t)N_NODES * sizeof(float);
    int*   rowseg  = (int*)  (ws + off); off += ((size_t)N_NODES * 2 + 16) * sizeof(int);
    int*   blkbin  = (int*)  (ws + off); off += (size_t)NBUCK * NBLK * sizeof(int);
    int*   blkpos  = (int*)  (ws + off); off += (size_t)NBUCK * NBLK * sizeof(int);
    int*   locoff  = (int*)  (ws + off); off += (size_t)NBLK * NBUCK * sizeof(int);
    int*   bintot  = (int*)  (ws + off); off += (size_t)NBUCK * sizeof(int);

    const int nb_wave = (NBUCK + 3) / 4;              // 98
    const int nb_n = (N_NODES + 255) / 256;           // 391
    const int nb_f = (N_NODES * 4 + 255) / 256;       // 1563 (4 thr/node)

    k_binfill<<<NBLK, 256, 0, stream>>>(ei, binned, blkbin, locoff);
    k_binwave<<<nb_wave, 256, 0, stream>>>(blkbin, bintot, blkpos);
    k_sortdeg<<<NBUCK, 512, 0, stream>>>(binned, blkbin, blkpos, locoff, bintot,
                                         csr16, rowseg, dinv);

    k_fc1_conv1<<<nb_n, 256, 0, stream>>>(x, Wfc1, bfc1, Wc1, dinv, gA);
    k_gather_mid<<<nb_f, 256, 0, stream>>>(rowseg, csr16, gA, dinv, bc1, Wc2, gB);
    k_gather_mid<<<nb_f, 256, 0, stream>>>(rowseg, csr16, gB, dinv, bc2, Wc3, gA);
    k_gather_out<<<nb_f, 256, 0, stream>>>(rowseg, csr16, gA, dinv, bc3, Wfc2, bfc2, out);
}

// Round 5
// 205.189 us; speedup vs baseline: 1.0680x; 1.0680x over previous
//
#include <hip/hip_runtime.h>
#include <hip/hip_fp16.h>

// GCN: 100K nodes, 2.5M edges, dims 4 -> 32 -> (32x32 conv x3) -> 3.
// R16: 16-bit quad CSR (QDIV=25000), 4-phase segmented gather, NBLK=512
//      scatter-free build, fp16 g, fp32 accumulate.  [219 us]
// R19: hierarchical wave-shuffle scans in build.  [215.7 us, best]
// R20: half CSR -> 219.1. REVERTED (1.6MB per-quad L2 hot set is load-
//      bearing; locality beats divergence at this operating point).
// R21: build memory-path fixes, gathers byte-identical to R19:
//      (a) k_sortdeg stages csr16 scatter in LDS (ushort outs[SCAP]) and
//          flushes coalesced — was 2.5M random 2B global stores.
//      (b) k_sortdeg run-copy reads binned via int4 after head-align —
//          was ~12.5 scalar 4B global loads per run.
//      (c) k_binfill caches (payload,bin) in LDS during the histogram pass
//          — scatter pass no longer re-reads ei from global (20MB saved).

constexpr int N_NODES = 100000;
constexpr int N_EDGES = 2500000;
constexpr int QDIV    = 25000;                             // src quad divisor
constexpr int BUCKET  = 256;
constexpr int NBUCK   = (N_NODES + BUCKET - 1) / BUCKET;   // 391
constexpr int NBLK    = 512;                               // build blocks
constexpr int CHUNK   = (N_EDGES + NBLK - 1) / NBLK;       // 4883
constexpr int SCAP    = 8192;                              // sortdeg LDS stage cap
constexpr int PERLANE = NBLK / 64;                         // 8

// ---- build K1: per-block LDS counting sort by bucket; contiguous write ----
__global__ __launch_bounds__(256) void k_binfill(const int* __restrict__ ei,
                                                 int* __restrict__ binned,
                                                 int* __restrict__ blkbin,
                                                 int* __restrict__ locoff) {
    __shared__ int cnt[NBUCK];
    __shared__ int cur[NBUCK];
    __shared__ int wsum[4];
    __shared__ int stage[CHUNK];
    __shared__ int payload[CHUNK];               // (src<<8)|dst_low8
    __shared__ unsigned short binv[CHUNK];       // dst>>8 (bucket id, <512)
    int tid = threadIdx.x;
    int blk = blockIdx.x;
    int beg = blk * CHUNK;
    int end = min(beg + CHUNK, N_EDGES);
    int m = end - beg;

    for (int i = tid; i < NBUCK; i += 256) cnt[i] = 0;
    __syncthreads();
    // pass 1: histogram + cache payload/bin in LDS (no global re-read later)
    for (int e = beg + tid; e < end; e += 256) {
        int sv = ei[e];
        int d  = ei[N_EDGES + e];
        int bin = d >> 8;
        atomicAdd(&cnt[bin], 1);
        int i = e - beg;
        payload[i] = (sv << 8) | (d & 255);
        binv[i] = (unsigned short)bin;
    }
    __syncthreads();

    // hierarchical shfl scan over 512 slots (2 per thread), 1 barrier.
    int c0 = (2 * tid     < NBUCK) ? cnt[2 * tid]     : 0;
    int c1 = (2 * tid + 1 < NBUCK) ? cnt[2 * tid + 1] : 0;
    int s  = c0 + c1;
    int incl = s;
#pragma unroll
    for (int o = 1; o < 64; o <<= 1) {
        int tm = __shfl_up(incl, o);
        if ((tid & 63) >= o) incl += tm;
    }
    if ((tid & 63) == 63) wsum[tid >> 6] = incl;
    __syncthreads();
    int wexcl = 0;
#pragma unroll
    for (int wi = 0; wi < 4; ++wi) wexcl += (wi < (tid >> 6)) ? wsum[wi] : 0;
    int texcl = wexcl + incl - s;              // exclusive prefix at slot 2*tid
    {
        int i = 2 * tid;
        if (i < NBUCK) {
            cur[i] = texcl;
            blkbin[i * NBLK + blk] = c0;
            locoff[blk * NBUCK + i] = beg + texcl;
        }
        i = 2 * tid + 1;
        if (i < NBUCK) {
            int e1 = texcl + c0;
            cur[i] = e1;
            blkbin[i * NBLK + blk] = c1;
            locoff[blk * NBUCK + i] = beg + e1;
        }
    }
    __syncthreads();

    // pass 2: scatter within LDS from the cached payload
    for (int i = tid; i < m; i += 256) {
        int pos = atomicAdd(&cur[binv[i]], 1);
        stage[pos] = payload[i];
    }
    __syncthreads();
    for (int i = tid; i < m; i += 256) binned[beg + i] = stage[i];  // coalesced
}

// ---- build K2: per-bin total + per-bin run-placement prefix (one wave/bin) ----
__global__ __launch_bounds__(256) void k_binwave(const int* __restrict__ blkbin,
                                                 int* __restrict__ bintot,
                                                 int* __restrict__ blkpos) {
    int w = threadIdx.x >> 6, lane = threadIdx.x & 63;
    int bin = blockIdx.x * 4 + w;
    if (bin >= NBUCK) return;
    int v[PERLANE];
#pragma unroll
    for (int i = 0; i < PERLANE; ++i) v[i] = blkbin[bin * NBLK + lane * PERLANE + i];
    int mysum = 0;
#pragma unroll
    for (int i = 0; i < PERLANE; ++i) mysum += v[i];
    int pre = mysum;
#pragma unroll
    for (int o = 1; o < 64; o <<= 1) {
        int t = __shfl_up(pre, o);
        if (lane >= o) pre += t;
    }
    int excl = pre - mysum;
    int run = excl;
#pragma unroll
    for (int i = 0; i < PERLANE; ++i) {
        blkpos[bin * NBLK + lane * PERLANE + i] = run;
        run += v[i];
    }
    if (lane == 63) bintot[bin] = pre;
}

// ---- build K3: per-bucket 1024-key sort (dst_local*4 + src_quad) ----
// Emits ushort csr (src - quad*QDIV) via LDS staging + coalesced flush.
__global__ __launch_bounds__(512) void k_sortdeg(const int* __restrict__ binned,
                                                 const int* __restrict__ blkbin,
                                                 const int* __restrict__ blkpos,
                                                 const int* __restrict__ locoff,
                                                 const int* __restrict__ bintot,
                                                 unsigned short* __restrict__ csr16,
                                                 int* __restrict__ rowseg,
                                                 float* __restrict__ dinv) {
    __shared__ int stage[SCAP];          // 32 KB
    __shared__ unsigned short outs[SCAP];// 16 KB (csr16 staging)
    __shared__ int runlen[NBLK];         // 2 KB
    __shared__ int runpos[NBLK];         // 2 KB
    __shared__ int cnt[1024];            // 4 KB
    __shared__ int sc[1024];             // 4 KB
    __shared__ int cur[1024];            // 4 KB
    __shared__ int wred[8];
    __shared__ int wtot[8];
    int t = threadIdx.x;
    int b = blockIdx.x;

    // bucket offset via wave-reduce (1 barrier)
    int part = 0;
    for (int i = t; i < b; i += 512) part += bintot[i];
#pragma unroll
    for (int o = 32; o > 0; o >>= 1) part += __shfl_xor(part, o);
    if ((t & 63) == 0) wred[t >> 6] = part;

    if (t < NBLK) {
        runlen[t] = blkbin[b * NBLK + t];
        runpos[t] = blkpos[b * NBLK + t];
    }
    cnt[t] = 0; cnt[t + 512] = 0;
    __syncthreads();

    int beg = 0;
#pragma unroll
    for (int wi = 0; wi < 8; ++wi) beg += wred[wi];
    int end = beg + bintot[b];
    int total = end - beg;
    bool fits = (total <= SCAP);

    if (fits) {
        // run-copy: head-align then int4 vector reads of binned
        for (int blk = t; blk < NBLK; blk += 512) {
            int len = runlen[blk];
            int srcp = locoff[blk * NBUCK + b];
            int dstp = runpos[blk];
            int i = 0;
            while (i < len && ((srcp + i) & 3)) { stage[dstp + i] = binned[srcp + i]; ++i; }
            for (; i + 3 < len; i += 4) {
                int4 v = *(const int4*)(binned + srcp + i);
                stage[dstp + i]     = v.x;
                stage[dstp + i + 1] = v.y;
                stage[dstp + i + 2] = v.z;
                stage[dstp + i + 3] = v.w;
            }
            for (; i < len; ++i) stage[dstp + i] = binned[srcp + i];
        }
        __syncthreads();
        for (int k = t; k < total; k += 512) {
            int p = stage[k];
            int key = ((p & 255) << 2) | ((p >> 8) / QDIV);
            atomicAdd(&cnt[key], 1);
        }
    } else {   // overflow fallback (statistically never)
        for (int blk = t; blk < NBLK; blk += 512) {
            int len = runlen[blk];
            int srcp = locoff[blk * NBUCK + b];
            for (int i = 0; i < len; ++i) {
                int p = binned[srcp + i];
                int key = ((p & 255) << 2) | ((p >> 8) / QDIV);
                atomicAdd(&cnt[key], 1);
            }
        }
    }
    __syncthreads();

    // 1024-key exclusive scan via hierarchical shfl (2 barriers)
    int c0 = cnt[2 * t], c1 = cnt[2 * t + 1];
    int s = c0 + c1;
    int incl = s;
#pragma unroll
    for (int o = 1; o < 64; o <<= 1) {
        int tm = __shfl_up(incl, o);
        if ((t & 63) >= o) incl += tm;
    }
    if ((t & 63) == 63) wtot[t >> 6] = incl;
    __syncthreads();
    int wexcl = 0;
#pragma unroll
    for (int wi = 0; wi < 8; ++wi) wexcl += (wi < (t >> 6)) ? wtot[wi] : 0;
    int texcl = wexcl + incl - s;              // exclusive prefix at slot 2t
    sc[2 * t]     = texcl + c0;                // inclusive values (downstream
    sc[2 * t + 1] = texcl + s;                 //   needs sc[k+3])
    __syncthreads();

#pragma unroll
    for (int slot = 0; slot < 2; ++slot) {
        int k = 2 * t + slot;
        int excl = (slot == 0) ? texcl : (texcl + c0);
        cur[k] = excl;
        int dl = k >> 2, q = k & 3;
        int n = b * BUCKET + dl;
        if (n < N_NODES) {
            rowseg[n * 4 + q] = beg + excl;
            if (q == 0) {
                int deg = sc[k + 3] - excl;          // sum of the 4 quads
                dinv[n] = rsqrtf((float)(deg + 1));  // +1 self-loop
            }
        }
    }
    if (b == NBUCK - 1 && t == 0) rowseg[(size_t)N_NODES * 4] = end;  // sentinel
    __syncthreads();

    if (fits) {
        for (int k = t; k < total; k += 512) {
            int p = stage[k];
            int src = p >> 8;
            int q = src / QDIV;
            int key = ((p & 255) << 2) | q;
            int pos = atomicAdd(&cur[key], 1);
            outs[pos] = (unsigned short)(src - q * QDIV);   // LDS scatter
        }
        __syncthreads();
        for (int k = t; k < total; k += 512)
            csr16[beg + k] = outs[k];                        // coalesced flush
    } else {
        for (int blk = t; blk < NBLK; blk += 512) {
            int len = runlen[blk];
            int srcp = locoff[blk * NBUCK + b];
            for (int i = 0; i < len; ++i) {
                int p = binned[srcp + i];
                int src = p >> 8;
                int q = src / QDIV;
                int key = ((p & 255) << 2) | q;
                int pos = atomicAdd(&cur[key], 1);
                csr16[beg + pos] = (unsigned short)(src - q * QDIV);
            }
        }
    }
}

// ================= dense helpers =================
__device__ inline void store_half8(__half* p, const float* v) {
    __half2 h[4];
#pragma unroll
    for (int i = 0; i < 4; ++i)
        h[i] = __floats2half2_rn(v[2 * i], v[2 * i + 1]);
    *(float4*)p = *(float4*)h;
}

__device__ inline void acc_half8(float* acc, float4 raw) {
    __half2* hp = (__half2*)&raw;
#pragma unroll
    for (int i = 0; i < 4; ++i) {
        float2 f = __half22float2(hp[i]);
        acc[2 * i]     += f.x;
        acc[2 * i + 1] += f.y;
    }
}

// t = relu(x@Wfc1 + bfc1); g = half( dinv * (t@Wc1) )
__global__ __launch_bounds__(256) void k_fc1_conv1(
        const float* __restrict__ x,
        const float* __restrict__ Wfc1, const float* __restrict__ bfc1,
        const float* __restrict__ Wc1, const float* __restrict__ dinv,
        __half* __restrict__ g) {
    __shared__ float  sWf[128];
    __shared__ float  sbf[32];
    __shared__ float4 sW[256];
    if (threadIdx.x < 128) sWf[threadIdx.x] = Wfc1[threadIdx.x];
    if (threadIdx.x < 32)  sbf[threadIdx.x] = bfc1[threadIdx.x];
    sW[threadIdx.x] = ((const float4*)Wc1)[threadIdx.x];
    __syncthreads();

    int n = blockIdx.x * 256 + threadIdx.x;
    if (n >= N_NODES) return;

    float4 xin = *(const float4*)(x + (size_t)n * 4);
    float t[32];
#pragma unroll
    for (int j = 0; j < 32; ++j) {
        float a = fmaf(xin.x, sWf[j], sbf[j]);
        a = fmaf(xin.y, sWf[32 + j], a);
        a = fmaf(xin.z, sWf[64 + j], a);
        a = fmaf(xin.w, sWf[96 + j], a);
        t[j] = fmaxf(a, 0.0f);
    }
    float o[32];
#pragma unroll
    for (int j = 0; j < 32; ++j) o[j] = 0.f;
#pragma unroll
    for (int k = 0; k < 32; ++k) {
        float a = t[k];
#pragma unroll
        for (int q = 0; q < 8; ++q) {
            float4 w = sW[k * 8 + q];
            o[q * 4 + 0] = fmaf(a, w.x, o[q * 4 + 0]);
            o[q * 4 + 1] = fmaf(a, w.y, o[q * 4 + 1]);
            o[q * 4 + 2] = fmaf(a, w.z, o[q * 4 + 2]);
            o[q * 4 + 3] = fmaf(a, w.w, o[q * 4 + 3]);
        }
    }
    float dv = dinv[n];
#pragma unroll
    for (int j = 0; j < 32; ++j) o[j] *= dv;
    __half* gp = g + (size_t)n * 32;
    store_half8(gp,      o);
    store_half8(gp + 8,  o + 8);
    store_half8(gp + 16, o + 16);
    store_half8(gp + 24, o + 24);
}

// ---- edge-segment accumulate over ushort csr: src = base + off ----
// (exact R16 form: 4-wide pipelined main loop + scalar remainder)
__device__ inline void gather_seg(int beg, int end, int base,
                                  const unsigned short* __restrict__ csr16,
                                  const __half* __restrict__ gin, int sub, float* acc) {
    int k = beg;
    int stop = beg + ((end - beg) & ~3);
    if (k < stop) {
        int s0 = base + csr16[k],     s1 = base + csr16[k + 1];
        int s2 = base + csr16[k + 2], s3 = base + csr16[k + 3];
        k += 4;
        while (k < stop) {
            float4 r0 = *(const float4*)(gin + (size_t)s0 * 32 + sub * 8);
            float4 r1 = *(const float4*)(gin + (size_t)s1 * 32 + sub * 8);
            float4 r2 = *(const float4*)(gin + (size_t)s2 * 32 + sub * 8);
            float4 r3 = *(const float4*)(gin + (size_t)s3 * 32 + sub * 8);
            s0 = base + csr16[k];     s1 = base + csr16[k + 1];
            s2 = base + csr16[k + 2]; s3 = base + csr16[k + 3];
            acc_half8(acc, r0); acc_half8(acc, r1);
            acc_half8(acc, r2); acc_half8(acc, r3);
            k += 4;
        }
        float4 r0 = *(const float4*)(gin + (size_t)s0 * 32 + sub * 8);
        float4 r1 = *(const float4*)(gin + (size_t)s1 * 32 + sub * 8);
        float4 r2 = *(const float4*)(gin + (size_t)s2 * 32 + sub * 8);
        float4 r3 = *(const float4*)(gin + (size_t)s3 * 32 + sub * 8);
        acc_half8(acc, r0); acc_half8(acc, r1);
        acc_half8(acc, r2); acc_half8(acc, r3);
    }
    for (; k < end; ++k) {
        int s = base + csr16[k];
        float4 r = *(const float4*)(gin + (size_t)s * 32 + sub * 8);
        acc_half8(acc, r);
    }
}

// ---- 4-phase soft gather + mid MLP: 4 threads/node, 64 nodes/block ----
// Per-segment calls act as wave-level phase barriers (SIMT lockstep).
__global__ __launch_bounds__(256) void k_gather_mid(
        const int* __restrict__ rowseg,
        const unsigned short* __restrict__ csr16, const __half* __restrict__ gin,
        const float* __restrict__ dinv,
        const float* __restrict__ b, const float* __restrict__ W,
        __half* __restrict__ gout) {
    __shared__ float sS[64 * 33];
    __shared__ float sW[1024];
    __shared__ float sb[32];
    for (int i = threadIdx.x; i < 1024; i += 256) sW[i] = W[i];
    if (threadIdx.x < 32) sb[threadIdx.x] = b[threadIdx.x];

    int nl = threadIdx.x >> 2;
    int sub = threadIdx.x & 3;
    int n = blockIdx.x * 64 + nl;
    float acc[8];
    if (n < N_NODES) {
        float4 self = *(const float4*)(gin + (size_t)n * 32 + sub * 8);
        {
            __half2* hp = (__half2*)&self;
#pragma unroll
            for (int i = 0; i < 4; ++i) {
                float2 f = __half22float2(hp[i]);
                acc[2 * i] = f.x;
                acc[2 * i + 1] = f.y;
            }
        }
        int4 seg = *(const int4*)(rowseg + (size_t)n * 4);
        int segend = rowseg[(size_t)n * 4 + 4];          // next start / sentinel
        gather_seg(seg.x, seg.y, 0,         csr16, gin, sub, acc);   // quad 0
        gather_seg(seg.y, seg.z, QDIV,      csr16, gin, sub, acc);   // quad 1
        gather_seg(seg.z, seg.w, 2 * QDIV,  csr16, gin, sub, acc);   // quad 2
        gather_seg(seg.w, segend, 3 * QDIV, csr16, gin, sub, acc);   // quad 3
#pragma unroll
        for (int i = 0; i < 8; ++i) sS[nl * 33 + sub * 8 + i] = acc[i];
    }
    __syncthreads();

    if (n >= N_NODES) return;
    float dv = dinv[n];
    float t[32];
#pragma unroll
    for (int kk = 0; kk < 32; ++kk)
        t[kk] = fmaxf(fmaf(dv, sS[nl * 33 + kk], sb[kk]), 0.0f);
    float o[8];
#pragma unroll
    for (int j = 0; j < 8; ++j) o[j] = 0.f;
#pragma unroll
    for (int kk = 0; kk < 32; ++kk) {
        float a = t[kk];
#pragma unroll
        for (int j = 0; j < 8; ++j)
            o[j] = fmaf(a, sW[kk * 32 + sub * 8 + j], o[j]);
    }
#pragma unroll
    for (int j = 0; j < 8; ++j) o[j] *= dv;
    store_half8(gout + (size_t)n * 32 + sub * 8, o);
}

// ---- 4-phase soft gather + final layer ----
__global__ __launch_bounds__(256) void k_gather_out(
        const int* __restrict__ rowseg,
        const unsigned short* __restrict__ csr16, const __half* __restrict__ gin,
        const float* __restrict__ dinv,
        const float* __restrict__ bc3, const float* __restrict__ Wfc2,
        const float* __restrict__ bfc2, float* __restrict__ out) {
    __shared__ float sS[64 * 33];
    __shared__ float sW[96];
    __shared__ float sb[32];
    __shared__ float sb2[3];
    if (threadIdx.x < 96) sW[threadIdx.x] = Wfc2[threadIdx.x];
    if (threadIdx.x < 32) sb[threadIdx.x] = bc3[threadIdx.x];
    if (threadIdx.x < 3)  sb2[threadIdx.x] = bfc2[threadIdx.x];

    int nl = threadIdx.x >> 2;
    int sub = threadIdx.x & 3;
    int n = blockIdx.x * 64 + nl;
    float acc[8];
    if (n < N_NODES) {
        float4 self = *(const float4*)(gin + (size_t)n * 32 + sub * 8);
        {
            __half2* hp = (__half2*)&self;
#pragma unroll
            for (int i = 0; i < 4; ++i) {
                float2 f = __half22float2(hp[i]);
                acc[2 * i] = f.x;
                acc[2 * i + 1] = f.y;
            }
        }
        int4 seg = *(const int4*)(rowseg + (size_t)n * 4);
        int segend = rowseg[(size_t)n * 4 + 4];
        gather_seg(seg.x, seg.y, 0,         csr16, gin, sub, acc);
        gather_seg(seg.y, seg.z, QDIV,      csr16, gin, sub, acc);
        gather_seg(seg.z, seg.w, 2 * QDIV,  csr16, gin, sub, acc);
        gather_seg(seg.w, segend, 3 * QDIV, csr16, gin, sub, acc);
#pragma unroll
        for (int i = 0; i < 8; ++i) sS[nl * 33 + sub * 8 + i] = acc[i];
    }
    __syncthreads();

    if (n >= N_NODES || sub != 0) return;
    float dv = dinv[n];
    float t[32];
#pragma unroll
    for (int kk = 0; kk < 32; ++kk)
        t[kk] = fmaxf(fmaf(dv, sS[nl * 33 + kk], sb[kk]), 0.0f);
    float o0 = sb2[0], o1 = sb2[1], o2 = sb2[2];
#pragma unroll
    for (int kk = 0; kk < 32; ++kk) {
        o0 = fmaf(t[kk], sW[kk * 3 + 0], o0);
        o1 = fmaf(t[kk], sW[kk * 3 + 1], o1);
        o2 = fmaf(t[kk], sW[kk * 3 + 2], o2);
    }
    out[(size_t)n * 3 + 0] = o0;
    out[(size_t)n * 3 + 1] = o1;
    out[(size_t)n * 3 + 2] = o2;
}

extern "C" void kernel_launch(void* const* d_in, const int* in_sizes, int n_in,
                              void* d_out, int out_size, void* d_ws, size_t ws_size,
                              hipStream_t stream) {
    const float* x    = (const float*)d_in[0];
    const int*   ei   = (const int*)d_in[1];
    const float* Wfc1 = (const float*)d_in[2];
    const float* bfc1 = (const float*)d_in[3];
    const float* Wc1  = (const float*)d_in[4];
    const float* bc1  = (const float*)d_in[5];
    const float* Wc2  = (const float*)d_in[6];
    const float* bc2  = (const float*)d_in[7];
    const float* Wc3  = (const float*)d_in[8];
    const float* bc3  = (const float*)d_in[9];
    const float* Wfc2 = (const float*)d_in[10];
    const float* bfc2 = (const float*)d_in[11];
    float* out = (float*)d_out;

    char* ws = (char*)d_ws;
    const size_t grow = (size_t)N_NODES * 32 * sizeof(__half);   // 6.4 MB
    size_t off = 0;
    __half* gA     = (__half*)(ws + off); off += grow;
    __half* gB     = (__half*)(ws + off); off += grow;
    int*   binned  = (int*)  (ws + off); off += (size_t)NBLK * CHUNK * sizeof(int);
    unsigned short* csr16 = (unsigned short*)(ws + off);
    off += ((size_t)N_EDGES + 8) * sizeof(unsigned short);
    float* dinv    = (float*)(ws + off); off += (size_t)N_NODES * sizeof(float);
    int*   rowseg  = (int*)  (ws + off); off += ((size_t)N_NODES * 4 + 16) * sizeof(int);
    int*   blkbin  = (int*)  (ws + off); off += (size_t)NBUCK * NBLK * sizeof(int);
    int*   blkpos  = (int*)  (ws + off); off += (size_t)NBUCK * NBLK * sizeof(int);
    int*   locoff  = (int*)  (ws + off); off += (size_t)NBLK * NBUCK * sizeof(int);
    int*   bintot  = (int*)  (ws + off); off += (size_t)NBUCK * sizeof(int);

    const int nb_wave = (NBUCK + 3) / 4;              // 98
    const int nb_n = (N_NODES + 255) / 256;           // 391
    const int nb_f = (N_NODES * 4 + 255) / 256;       // 1563 (4 thr/node)

    k_binfill<<<NBLK, 256, 0, stream>>>(ei, binned, blkbin, locoff);
    k_binwave<<<nb_wave, 256, 0, stream>>>(blkbin, bintot, blkpos);
    k_sortdeg<<<NBUCK, 512, 0, stream>>>(binned, blkbin, blkpos, locoff, bintot,
                                         csr16, rowseg, dinv);

    k_fc1_conv1<<<nb_n, 256, 0, stream>>>(x, Wfc1, bfc1, Wc1, dinv, gA);
    k_gather_mid<<<nb_f, 256, 0, stream>>>(rowseg, csr16, gA, dinv, bc1, Wc2, gB);
    k_gather_mid<<<nb_f, 256, 0, stream>>>(rowseg, csr16, gB, dinv, bc2, Wc3, gA);
    k_gather_out<<<nb_f, 256, 0, stream>>>(rowseg, csr16, gA, dinv, bc3, Wfc2, bfc2, out);
}